// Round 12
// baseline (1998.048 us; speedup 1.0000x reference)
//
#include <hip/hip_runtime.h>
#include <hip/hip_bf16.h>
#include <math.h>

typedef __hip_bfloat16 bf16;
typedef short s16x8 __attribute__((ext_vector_type(8)));
typedef float f32x4 __attribute__((ext_vector_type(4)));

#define NN 50000
#define EE 150000
#define EH 75000   // linkpred edge-chunk (2 halves)

static __device__ __forceinline__ float b2f(bf16 x){ return __bfloat162float(x); }
static __device__ __forceinline__ bf16 f2b(float x){ return __float2bfloat16(x); }
static __device__ __forceinline__ short f2s(float x){
  union { bf16 b; short s; } u; u.b = f2b(x); return u.s;
}
static __device__ __forceinline__ float u2f_lo(unsigned u){ union{unsigned i;float f;}c; c.i=u<<16; return c.f; }
static __device__ __forceinline__ float u2f_hi(unsigned u){ union{unsigned i;float f;}c; c.i=u&0xffff0000u; return c.f; }

// fast tanh: 1 - 2/(e^{2|x|}+1), sign-restored. |err| ~1e-5 << bf16 quantum.
static __device__ __forceinline__ float fast_tanh(float x){
  float a = fabsf(x);
  float e = __expf(2.0f*a);
  float t = 1.0f - __fdividef(2.0f, e + 1.0f);
  return x < 0.f ? -t : t;
}

static __device__ __forceinline__ void gload_lds16(const void* g, void* l){
  __builtin_amdgcn_global_load_lds((const __attribute__((address_space(1))) void*)g,
                                   (__attribute__((address_space(3))) void*)l, 16, 0, 0);
}

template<int N> static __device__ __forceinline__ void wait_vmcnt(){
  if constexpr(N==0) asm volatile("s_waitcnt vmcnt(0)" ::: "memory");
  else if constexpr(N==1) asm volatile("s_waitcnt vmcnt(1)" ::: "memory");
  else if constexpr(N==2) asm volatile("s_waitcnt vmcnt(2)" ::: "memory");
  else if constexpr(N==3) asm volatile("s_waitcnt vmcnt(3)" ::: "memory");
  else if constexpr(N==4) asm volatile("s_waitcnt vmcnt(4)" ::: "memory");
  else if constexpr(N==5) asm volatile("s_waitcnt vmcnt(5)" ::: "memory");
  else asm volatile("s_waitcnt vmcnt(6)" ::: "memory");
}
static __device__ __forceinline__ void wait_lgkm0(){
  asm volatile("s_waitcnt lgkmcnt(0)" ::: "memory");
}
static __device__ __forceinline__ void memfence(){
  asm volatile("" ::: "memory");
}

// ---------------- utility ----------------
__global__ void k_zero(int* __restrict__ p, int n){
  int i = blockIdx.x*blockDim.x + threadIdx.x;
  if(i<n) p[i]=0;
}

// ---------------- CSR build ----------------
__global__ void k_hist(const int* __restrict__ dst, int* __restrict__ deg){
  int i = blockIdx.x*blockDim.x + threadIdx.x;
  if(i<EE) atomicAdd(&deg[dst[i]], 1);
}

__global__ void k_scan(const int* __restrict__ deg, int* __restrict__ rowptr){
  __shared__ int part[1024];
  int tid = threadIdx.x;
  const int n = NN;
  int chunk = (n + 1023)/1024;
  int start = tid*chunk;
  int end = start + chunk; if(end > n) end = n;
  int s = 0;
  for(int i=start;i<end;i++) s += deg[i];
  part[tid] = s; __syncthreads();
  for(int off=1; off<1024; off<<=1){
    int v = (tid>=off)? part[tid-off] : 0;
    __syncthreads();
    part[tid] += v;
    __syncthreads();
  }
  int run = (tid==0)? 0 : part[tid-1];
  for(int i=start;i<end;i++){ rowptr[i]=run; run += deg[i]; }
  if(tid==0) rowptr[n] = part[1023];
}

// also emits ssrc[j] = src[elist[j]] so attn streams src ids in CSR order
__global__ void k_scatter(const int* __restrict__ dst, const int* __restrict__ srcv,
                          const int* __restrict__ rowptr,
                          int* __restrict__ cursor, int* __restrict__ elist,
                          int* __restrict__ ssrc){
  int e = blockIdx.x*blockDim.x + threadIdx.x;
  if(e<EE){
    int d=dst[e]; int p=atomicAdd(&cursor[d],1);
    int pos = rowptr[d]+p;
    elist[pos]=e; ssrc[pos]=srcv[e];
  }
}

// ------- time encoding -> relc [E,112] in CSR ORDER (cols 100..111 zero) -------
__global__ void k_relenc(const int* __restrict__ elist, const int* __restrict__ ssrc,
                         const int* __restrict__ tt, const int* __restrict__ lu,
                         const float* __restrict__ tw, const float* __restrict__ tb,
                         bf16* __restrict__ rel){
  int i = blockIdx.x*blockDim.x + threadIdx.x;
  if(i >= EE*112) return;
  int j = i/112, c = i - j*112;
  float v = 0.f;
  if(c < 100){
    int e = elist[j];
    float rt  = (float)(lu[ssrc[j]] - tt[e]);
    float arg = __fadd_rn(__fmul_rn(rt, tw[c]), tb[c]);
    v = cosf(arg);
  }
  rel[i] = f2b(v);
}

// ------- fp32 [R][incols] -> bf16 [R][outcols] row-major, zero-padded ----
__global__ void k_cvtpad(const float* __restrict__ in, int incols,
                         bf16* __restrict__ outp, int outcols, int total){
  int i = blockIdx.x*blockDim.x + threadIdx.x;
  if(i >= total) return;
  int r = i/outcols, c = i - r*outcols;
  outp[i] = f2b(c < incols ? in[(size_t)r*incols + c] : 0.f);
}

// ------- generic weight transpose: WT[n][k] = W[k][colofs+n], bf16, zero-pad ----
__global__ void k_wt2(const float* __restrict__ W, int K, int N, int colofs, int ncols,
                      bf16* __restrict__ WT, int kpad, int nrows){
  int i = blockIdx.x*blockDim.x + threadIdx.x;
  if(i >= nrows*kpad) return;
  int n = i / kpad, k = i - n*kpad;
  float v = (n<ncols && k<K)? W[(size_t)k*N + colofs + n] : 0.f;
  WT[i] = f2b(v);
}

// ------- conv1 stacked qkv weights: 8 heads x [320 rows: q|k|v|pad][128] -----
__global__ void k_wtc1(const float* __restrict__ qw, const float* __restrict__ kw,
                       const float* __restrict__ vw, bf16* __restrict__ outp){
  int i = blockIdx.x*blockDim.x + threadIdx.x;
  if(i >= 8*320*128) return;
  int h = i/(320*128), r = (i/128)%320, k = i&127;
  float v = 0.f;
  if(r < 300 && k < 100){
    int s = r/100, n = r - s*100;
    const float* W = s==0? qw : s==1? kw : vw;
    v = W[(size_t)k*800 + h*100 + n];
  }
  outp[i] = f2b(v);
}

// ------- edge weights [112][256]: k<100 -> rel rows, 128..227 -> msg rows ---
// cols k in [100,128) and [228,256) are ZERO — mm_edge relies on this to
// neutralize clamped/garbage A lanes.
__global__ void k_wte(const float* __restrict__ ew, int N, int colofs,
                      bf16* __restrict__ outp){
  int i = blockIdx.x*blockDim.x + threadIdx.x;
  if(i >= 112*256) return;
  int r = i>>8, k = i&255;
  float v = 0.f;
  if(r < 100){
    if(k < 100) v = ew[(size_t)k*N + colofs + r];
    else if(k >= 128 && k < 228) v = ew[(size_t)(k-28)*N + colofs + r];
  }
  outp[i] = f2b(v);
}

// ------- stacked qkv bias: [H][3*W] ----------------
__global__ void k_bstack3(const float* __restrict__ b0, const float* __restrict__ b1,
                          const float* __restrict__ b2, int W, int H,
                          float* __restrict__ outp){
  int i = blockIdx.x*blockDim.x + threadIdx.x;
  if(i >= H*3*W) return;
  int h = i/(3*W), r = i - h*3*W, s = r/W, c = r - s*W;
  const float* b = s==0? b0 : s==1? b1 : b2;
  outp[i] = b[h*W + c];
}

// ------- linkpred fold: WT1f[n][k] bf16, [800][224] ------------------------------
__global__ void k_foldw(const float* __restrict__ sw, const float* __restrict__ dw,
                        const float* __restrict__ w1, bf16* __restrict__ o){
  int i = blockIdx.x*blockDim.x + threadIdx.x;
  if(i >= 800*224) return;
  int n = i/224, k = i - n*224;
  float s = 0.f;
  if(k < 100){
    for(int j=0;j<200;j++) s += sw[k*200+j]*w1[(size_t)j*800+n];
  } else if(k >= 112 && k < 212){
    int kk = k-112;
    for(int j=0;j<200;j++) s += dw[kk*200+j]*w1[(size_t)(200+j)*800+n];
  }
  o[i] = f2b(s);
}
__global__ void k_foldb(const float* __restrict__ sb, const float* __restrict__ db,
                        const float* __restrict__ w1, const float* __restrict__ b1,
                        float* __restrict__ o){
  int n = blockIdx.x*blockDim.x + threadIdx.x;
  if(n >= 800) return;
  float s = b1[n];
  for(int j=0;j<200;j++) s += sb[j]*w1[(size_t)j*800+n] + db[j]*w1[(size_t)(200+j)*800+n];
  o[n] = s;
}

// ---------------- counted-vmcnt ring-pipelined MFMA GEMM (BK=32, 3 bufs) --------
// (see R3 comments; one instantiation per kernel — R4 multi-inst segfaulted clang)
template<int NT>
static __device__ void mm_body(
    char* lds, int bx, int nstrip,
    const bf16* __restrict__ A1, int lda1, int kv1, const int* __restrict__ g1,
    int KS,
    const bf16* __restrict__ A2b, int lda2b, int kv2b, const int* __restrict__ g2,
    const float* __restrict__ A2f, int lda2f, int kv2f,
    const bf16* __restrict__ WT, int kpad,
    const bf16* __restrict__ zbuf,
    const float* __restrict__ bias,
    bf16* __restrict__ C, int ldc,
    int M, int nvalid, int act)
{
  constexpr int BN = NT*16;
  constexpr int BPASS = (BN*4 + 255)/256;
  constexpr int ABYTES = 8192;
  constexpr int BUFSZ = ABYTES + BPASS*4096;

  const int tid  = threadIdx.x;
  const int wave = tid>>6, lane = tid&63;
  const int quad = lane>>4, lo = lane&15;
  WT += (size_t)nstrip*BN*kpad;
  C  += (size_t)nstrip*BN;
  if(bias) bias += nstrip*BN;
  const int nval = nvalid - nstrip*BN;
  const int row0 = bx*128;

  float bvr[NT];
#pragma unroll
  for(int n=0;n<NT;n++){
    int col = n*16 + lo;
    bvr[n] = (bias && col < nval) ? bias[col] : 0.f;
  }
#pragma unroll
  for(int n=0;n<NT;n++) asm volatile("" :: "v"(bvr[n]));

  const char*  a1b[2];
  const char*  a2bp[2];
  const float* f2base[2];
  int acol0[2];
#pragma unroll
  for(int p=0;p<2;p++){
    int s = p*256 + tid;
    int row = s>>2, cp = s&3;
    int q = cp ^ ((row>>1)&3);
    int col0 = q*8;
    int rg = row0 + row; if(rg > M-1) rg = M-1;
    int r1 = g1 ? g1[rg] : rg;
    int r2 = g2 ? g2[rg] : rg;
    acol0[p] = col0;
    a1b[p]   = (const char*)A1 + ((size_t)r1*lda1 + col0)*2;
    a2bp[p]  = A2b ? (const char*)A2b + ((size_t)r2*lda2b)*2 : nullptr;
    f2base[p]= A2f ? (A2f + (size_t)r2*lda2f) : nullptr;
  }
  const char* bbase[BPASS];
#pragma unroll
  for(int p=0;p<BPASS;p++){
    int s = p*256 + tid;
    int rb = s>>2; if(rb > BN-1) rb = BN-1;
    int cp = s&3;
    int lq = cp ^ ((rb>>1)&3);
    bbase[p] = (const char*)WT + ((size_t)rb*kpad + lq*8)*2;
  }

  f32x4 acc[2][NT];
#pragma unroll
  for(int m=0;m<2;m++)
#pragma unroll
    for(int n=0;n<NT;n++) acc[m][n] = (f32x4){0.f,0.f,0.f,0.f};

  float4 pf0[2], pf1[2];

  auto stageA1 = [&](char* buf, int kb){
#pragma unroll
    for(int p=0;p<2;p++){
      int k = kb + acol0[p];
      const char* s;
      if(k < KS) s = (k < kv1) ? (a1b[p] + (size_t)kb*2) : (const char*)zbuf;
      else { int o = k - KS; s = (o < kv2b) ? (a2bp[p] + (size_t)o*2) : (const char*)zbuf; }
      gload_lds16(s, buf + p*4096 + wave*1024);
    }
  };
  auto loadA2f = [&](int kb){
#pragma unroll
    for(int p=0;p<2;p++){
      int o = kb + acol0[p] - KS;
      const float* ap = f2base[p] + o;
      pf0[p] = (o   < kv2f) ? *(const float4*)ap     : (float4){0.f,0.f,0.f,0.f};
      pf1[p] = (o+4 < kv2f) ? *(const float4*)(ap+4) : (float4){0.f,0.f,0.f,0.f};
    }
  };
  auto writeA2 = [&](char* buf){
#pragma unroll
    for(int p=0;p<2;p++){
      s16x8 v;
      v[0]=f2s(pf0[p].x); v[1]=f2s(pf0[p].y); v[2]=f2s(pf0[p].z); v[3]=f2s(pf0[p].w);
      v[4]=f2s(pf1[p].x); v[5]=f2s(pf1[p].y); v[6]=f2s(pf1[p].z); v[7]=f2s(pf1[p].w);
      *(s16x8*)(buf + p*4096 + (size_t)tid*16) = v;
    }
  };
  auto stageB = [&](char* buf, int kb){
#pragma unroll
    for(int p=0;p<BPASS;p++)
      gload_lds16(bbase[p] + (size_t)kb*2, buf + ABYTES + p*4096 + wave*1024);
  };
  auto compute = [&](const char* buf){
    s16x8 af[2];
#pragma unroll
    for(int m=0;m<2;m++){
      int rl = wave*32 + m*16 + lo;
      int cp = quad ^ ((rl>>1)&3);
      af[m] = *(const s16x8*)(buf + rl*64 + cp*16);
    }
#pragma unroll
    for(int n=0;n<NT;n++){
      int rb = n*16 + lo;
      int cp = quad ^ ((rb>>1)&3);
      s16x8 bfr = *(const s16x8*)(buf + ABYTES + rb*64 + cp*16);
      acc[0][n] = __builtin_amdgcn_mfma_f32_16x16x32_bf16(af[0], bfr, acc[0][n], 0,0,0);
      acc[1][n] = __builtin_amdgcn_mfma_f32_16x16x32_bf16(af[1], bfr, acc[1][n], 0,0,0);
    }
  };

  const int T = kpad >> 5;
  stageA1(lds, 0); stageB(lds, 0);
  if(T > 1){ stageA1(lds + BUFSZ, 32); stageB(lds + BUFSZ, 32); }

  for(int t=0; t<T; t++){
    bool nb  = (t+1 < T);
    bool nfp = nb && A2f && (((t+1)<<5) >= KS);
    if(!nb)      wait_vmcnt<0>();
    else if(nfp) wait_vmcnt<BPASS>();
    else         wait_vmcnt<2+BPASS>();
    wait_lgkm0();
    __builtin_amdgcn_s_barrier();
    memfence();
    int tp = t+2;
    bool sp  = (tp < T);
    bool spf = sp && A2f && ((tp<<5) >= KS);
    char* nb3 = lds + (tp%3)*BUFSZ;
    if(sp){
      int kb2 = tp<<5;
      if(spf) loadA2f(kb2);
      else    stageA1(nb3, kb2);
      stageB(nb3, kb2);
    }
    compute(lds + (t%3)*BUFSZ);
    if(spf) writeA2(nb3);
  }

  const int r0 = (lane&1)<<1;
#pragma unroll
  for(int n=0;n<NT;n++){
    int col  = n*16 + lo;
    int pcol = col & ~1;
    bool cok = (pcol < nval);
    float bv = bvr[n];
#pragma unroll
    for(int m=0;m<2;m++){
      float v[4];
#pragma unroll
      for(int r=0;r<4;r++){
        float t = acc[m][n][r] + bv;
        if(act==1) t = fmaxf(t, 0.f);
        else if(act==2) t = fast_tanh(t);
        v[r] = t;
      }
      unsigned mylo = (unsigned)(unsigned short)f2s(v[r0])
                    | ((unsigned)(unsigned short)f2s(v[r0+1])<<16);
      unsigned snd  = (unsigned)(unsigned short)f2s(v[r0^2])
                    | ((unsigned)(unsigned short)f2s(v[(r0^2)+1])<<16);
      unsigned got  = (unsigned)__shfl_xor((int)snd, 1);
      unsigned w0, w1;
      if(lane&1){ w0 = (got & 0xffffu) | (mylo<<16); w1 = (got>>16) | (mylo & 0xffff0000u); }
      else      { w0 = (mylo & 0xffffu) | (got<<16); w1 = (mylo>>16) | (got & 0xffff0000u); }
      if(cok){
        int prow = row0 + wave*32 + m*16 + quad*4 + r0;
        if(prow   < M) *(unsigned*)(C + (size_t)prow*ldc + pcol) = w0;
        if(prow+1 < M) *(unsigned*)(C + (size_t)(prow+1)*ldc + pcol) = w1;
      }
    }
  }
}

// standalone wrapper — one instantiation per NT
template<int NT>
__global__ __launch_bounds__(256) void mm_tile(
    const bf16* A1, int lda1, int kv1, const int* g1, int KS,
    const bf16* A2b, int lda2b, int kv2b, const int* g2,
    const float* A2f, int lda2f, int kv2f,
    const bf16* WT, int kpad, const bf16* zbuf, const float* bias,
    bf16* C, int ldc, int M, int nvalid, int act)
{
  constexpr int BUFSZ = 8192 + ((NT*16*4+255)/256)*4096;
  __shared__ __align__(16) char lds[3*BUFSZ];
  mm_body<NT>(lds, blockIdx.x, blockIdx.y, A1,lda1,kv1,g1, KS,
              A2b,lda2b,kv2b,g2, A2f,lda2f,kv2f, WT,kpad, zbuf, bias,
              C,ldc, M,nvalid,act);
}

// ---------- reg-gathered-A GEMM for t1 (K=224 fixed, dual src/dst gather) -------
// R8 form: blockIdx.y = n-strip (max TLP; gather re-read is the cheaper cost in
// this latency-bound regime — R11's strip-loop variant cut FETCH 95->25 MB but
// lost occupancy 20.6->8.8% and ran 1.6x slower).
template<int NT>
__global__ __launch_bounds__(256) void mm_gath(
    const bf16* __restrict__ A, int lda, int KS,
    const int* __restrict__ gs, const int* __restrict__ gd,
    const bf16* __restrict__ WT,
    const float* __restrict__ bias,
    bf16* __restrict__ C, int ldc,
    int M, int nvalid, int act)
{
  constexpr int T = 7;           // kpad = 224
  constexpr int KPAD = 224;
  constexpr int BN = NT*16;
  constexpr int BPASS = (BN*4 + 255)/256;
  constexpr int BUFSZ = BPASS*4096;
  __shared__ __align__(16) char lds[3*BUFSZ];

  const int tid  = threadIdx.x;
  const int wave = tid>>6, lane = tid&63;
  const int quad = lane>>4, lo = lane&15;
  const int nstrip = blockIdx.y;
  const bf16* WTs = WT + (size_t)nstrip*BN*KPAD;
  C += (size_t)nstrip*BN;
  const float* bp = bias ? bias + nstrip*BN : nullptr;
  const int nval = nvalid - nstrip*BN;
  const int row0 = blockIdx.x*128;

  float bvr[NT];
#pragma unroll
  for(int n=0;n<NT;n++){
    int col = n*16 + lo;
    bvr[n] = (bp && col < nval) ? bp[col] : 0.f;
  }

  const bf16* abase[2][2];
#pragma unroll
  for(int m=0;m<2;m++){
    int r = row0 + wave*32 + m*16 + lo; if(r > M-1) r = M-1;
    abase[m][0] = A + (size_t)gs[r]*lda;
    abase[m][1] = A + (size_t)gd[r]*lda;
  }

  s16x8 areg[T][2];
#pragma unroll
  for(int t=0;t<T;t++){
#pragma unroll
    for(int m=0;m<2;m++){
      int k = t*32 + quad*8;
      const bf16* p = (k < KS) ? (abase[m][0] + k) : (abase[m][1] + (k - KS));
      asm volatile("global_load_dwordx4 %0, %1, off"
                   : "=v"(areg[t][m]) : "v"(p));
    }
  }
  memfence();

  const char* bbase[BPASS];
#pragma unroll
  for(int p=0;p<BPASS;p++){
    int s = p*256 + tid;
    int rb = s>>2; if(rb > BN-1) rb = BN-1;
    int cp = s&3;
    int lq = cp ^ ((rb>>1)&3);
    bbase[p] = (const char*)WTs + ((size_t)rb*KPAD + lq*8)*2;
  }
  auto stageB = [&](char* buf, int kb){
#pragma unroll
    for(int p=0;p<BPASS;p++)
      gload_lds16(bbase[p] + (size_t)kb*2, buf + p*4096 + wave*1024);
  };

  f32x4 acc[2][NT];
#pragma unroll
  for(int m=0;m<2;m++)
#pragma unroll
    for(int n=0;n<NT;n++) acc[m][n] = (f32x4){0.f,0.f,0.f,0.f};

  stageB(lds, 0);
  stageB(lds + BUFSZ, 32);

#pragma unroll
  for(int t=0; t<T; t++){
    if(t < T-1) wait_vmcnt<BPASS>();
    else        wait_vmcnt<0>();
    wait_lgkm0();
    __builtin_amdgcn_s_barrier();
    memfence();
    if(t+2 < T) stageB(lds + ((t+2)%3)*BUFSZ, (t+2)*32);
    const char* buf = lds + (t%3)*BUFSZ;
#pragma unroll
    for(int n=0;n<NT;n++){
      int rb = n*16 + lo;
      int cp = quad ^ ((rb>>1)&3);
      s16x8 bfr = *(const s16x8*)(buf + rb*64 + cp*16);
      acc[0][n] = __builtin_amdgcn_mfma_f32_16x16x32_bf16(areg[t][0], bfr, acc[0][n], 0,0,0);
      acc[1][n] = __builtin_amdgcn_mfma_f32_16x16x32_bf16(areg[t][1], bfr, acc[1][n], 0,0,0);
    }
  }

  const int r0 = (lane&1)<<1;
#pragma unroll
  for(int n=0;n<NT;n++){
    int col  = n*16 + lo;
    int pcol = col & ~1;
    bool cok = (pcol < nval);
    float bv = bvr[n];
#pragma unroll
    for(int m=0;m<2;m++){
      float v[4];
#pragma unroll
      for(int r=0;r<4;r++){
        float t = acc[m][n][r] + bv;
        if(act==1) t = fmaxf(t, 0.f);
        else if(act==2) t = fast_tanh(t);
        v[r] = t;
      }
      unsigned mylo = (unsigned)(unsigned short)f2s(v[r0])
                    | ((unsigned)(unsigned short)f2s(v[r0+1])<<16);
      unsigned snd  = (unsigned)(unsigned short)f2s(v[r0^2])
                    | ((unsigned)(unsigned short)f2s(v[(r0^2)+1])<<16);
      unsigned got  = (unsigned)__shfl_xor((int)snd, 1);
      unsigned w0, w1;
      if(lane&1){ w0 = (got & 0xffffu) | (mylo<<16); w1 = (got>>16) | (mylo & 0xffff0000u); }
      else      { w0 = (mylo & 0xffffu) | (got<<16); w1 = (mylo>>16) | (got & 0xffff0000u); }
      if(cok){
        int prow = row0 + wave*32 + m*16 + quad*4 + r0;
        if(prow   < M) *(unsigned*)(C + (size_t)prow*ldc + pcol) = w0;
        if(prow+1 < M) *(unsigned*)(C + (size_t)(prow+1)*ldc + pcol) = w1;
      }
    }
  }
}

// ---------- edge GEMM: ehc[j] = [relc[j] | msg[elist[j]]] @ WT  (K=256 fixed) ----
// All A fragments in REGISTERS up-front; B via 3-buffer LDS ring, counted vmcnt.
// Garbage/clamped A lanes neutralized by WT's zero cols [100,128) & [228,256).
__global__ __launch_bounds__(256) void mm_edge(
    const bf16* __restrict__ relc,     // [EE][112], CSR order
    const float* __restrict__ msg,     // [EE][100], natural edge order
    const int* __restrict__ elist,
    const bf16* __restrict__ WT,       // [112][256]
    bf16* __restrict__ C, int ldc,     // ehc [EE][100]
    int M)
{
  constexpr int NT = 7;
  constexpr int BN = 112;
  constexpr int BPASS = 2;             // ceil(BN*4/256)
  constexpr int KPAD = 256, T = 8;
  constexpr int BUFSZ = BPASS*4096;
  __shared__ __align__(16) char lds[3*BUFSZ];

  const int tid  = threadIdx.x;
  const int wave = tid>>6, lane = tid&63;
  const int quad = lane>>4, lo = lane&15;
  const int row0 = blockIdx.x*128;

  // A row bases
  const bf16*  arel[2];
  const float* amsg[2];
#pragma unroll
  for(int m=0;m<2;m++){
    int r = row0 + wave*32 + m*16 + lo; if(r > M-1) r = M-1;
    arel[m] = relc + (size_t)r*112;
    amsg[m] = msg + (size_t)elist[r]*100;
  }

  // relc fragments, tiles 0..3 (k<112 valid; clamp to 96 -> garbage x zero-B)
  s16x8 ar[4][2];
#pragma unroll
  for(int t=0;t<4;t++){
#pragma unroll
    for(int m=0;m<2;m++){
      int k = t*32 + quad*8;
      int kc = (k < 112) ? k : 96;
      ar[t][m] = *(const s16x8*)(arel[m] + kc);
    }
  }
  // msg fragments, tiles 4..7 (fp32, masked; invalid lanes hit zero-B cols)
  float4 mf0[4][2], mf1[4][2];
#pragma unroll
  for(int t=0;t<4;t++){
#pragma unroll
    for(int m=0;m<2;m++){
      int mk = t*32 + quad*8;
      mf0[t][m] = (mk   < 100) ? *(const float4*)(amsg[m] + mk)   : (float4){0.f,0.f,0.f,0.f};
      mf1[t][m] = (mk+4 < 100) ? *(const float4*)(amsg[m] + mk+4) : (float4){0.f,0.f,0.f,0.f};
    }
  }
  memfence();

  // B ring
  const char* bbase[BPASS];
#pragma unroll
  for(int p=0;p<BPASS;p++){
    int s = p*256 + tid;
    int rb = s>>2; if(rb > BN-1) rb = BN-1;
    int cp = s&3;
    int lq = cp ^ ((rb>>1)&3);
    bbase[p] = (const char*)WT + ((size_t)rb*KPAD + lq*8)*2;
  }
  auto stageB = [&](char* buf, int kb){
#pragma unroll
    for(int p=0;p<BPASS;p++)
      gload_lds16(bbase[p] + (size_t)kb*2, buf + p*4096 + wave*1024);
  };

  f32x4 acc[2][NT];
#pragma unroll
  for(int m=0;m<2;m++)
#pragma unroll
    for(int n=0;n<NT;n++) acc[m][n] = (f32x4){0.f,0.f,0.f,0.f};

  stageB(lds, 0);
  stageB(lds + BUFSZ, 32);

#pragma unroll
  for(int t=0; t<T; t++){
    if(t < T-1) wait_vmcnt<BPASS>();
    else        wait_vmcnt<0>();
    wait_lgkm0();
    __builtin_amdgcn_s_barrier();
    memfence();
    if(t+2 < T) stageB(lds + ((t+2)%3)*BUFSZ, (t+2)*32);
    const char* buf = lds + (t%3)*BUFSZ;
    s16x8 af[2];
    if(t < 4){
#pragma unroll
      for(int m=0;m<2;m++) af[m] = ar[t][m];
    } else {
#pragma unroll
      for(int m=0;m<2;m++){
        float4 f0 = mf0[t-4][m], f1 = mf1[t-4][m];
        s16x8 v;
        v[0]=f2s(f0.x); v[1]=f2s(f0.y); v[2]=f2s(f0.z); v[3]=f2s(f0.w);
        v[4]=f2s(f1.x); v[5]=f2s(f1.y); v[6]=f2s(f1.z); v[7]=f2s(f1.w);
        af[m] = v;
      }
    }
#pragma unroll
    for(int n=0;n<NT;n++){
      int rb = n*16 + lo;
      int cp = quad ^ ((rb>>1)&3);
      s16x8 bfr = *(const s16x8*)(buf + rb*64 + cp*16);
      acc[0][n] = __builtin_amdgcn_mfma_f32_16x16x32_bf16(af[0], bfr, acc[0][n], 0,0,0);
      acc[1][n] = __builtin_amdgcn_mfma_f32_16x16x32_bf16(af[1], bfr, acc[1][n], 0,0,0);
    }
  }

  // epilogue: no bias, no act, nval = 100
  const int r0 = (lane&1)<<1;
#pragma unroll
  for(int n=0;n<NT;n++){
    int col  = n*16 + lo;
    int pcol = col & ~1;
    bool cok = (pcol < 100);
#pragma unroll
    for(int m=0;m<2;m++){
      float v[4];
#pragma unroll
      for(int r=0;r<4;r++) v[r] = acc[m][n][r];
      unsigned mylo = (unsigned)(unsigned short)f2s(v[r0])
                    | ((unsigned)(unsigned short)f2s(v[r0+1])<<16);
      unsigned snd  = (unsigned)(unsigned short)f2s(v[r0^2])
                    | ((unsigned)(unsigned short)f2s(v[(r0^2)+1])<<16);
      unsigned got  = (unsigned)__shfl_xor((int)snd, 1);
      unsigned w0, w1;
      if(lane&1){ w0 = (got & 0xffffu) | (mylo<<16); w1 = (got>>16) | (mylo & 0xffff0000u); }
      else      { w0 = (mylo & 0xffffu) | (got<<16); w1 = (mylo>>16) | (got & 0xffff0000u); }
      if(cok){
        int prow = row0 + wave*32 + m*16 + quad*4 + r0;
        if(prow   < M) *(unsigned*)(C + (size_t)prow*ldc + pcol) = w0;
        if(prow+1 < M) *(unsigned*)(C + (size_t)(prow+1)*ldc + pcol) = w1;
      }
    }
  }
}

// ------ fused attention: one wave per node; online softmax; skip-add + relu ------
// 1-deep load prefetch: j+1's ssrc + k/v/e gathers issue before j's softmax math.
__global__ __launch_bounds__(256) void k_attn(
    const int* __restrict__ rowptr, const int* __restrict__ ssrc,
    const bf16* __restrict__ qkv, const bf16* __restrict__ ehc,
    bf16* __restrict__ hout, int ldh, int colofs, int zpad)
{
  int wave = threadIdx.x>>6, lane = threadIdx.x&63;
  int node = blockIdx.x*4 + wave;
  if(node >= NN) return;
  bool act = (lane < 50);
  float q0=0.f, q1=0.f;
  const unsigned* qrow = (const unsigned*)(qkv + (size_t)node*300);
  if(act){ unsigned u = qrow[lane]; q0=u2f_lo(u); q1=u2f_hi(u); }
  int s0 = rowptr[node], s1 = rowptr[node+1];
  float m = -3.4e38f, d = 0.f, a0 = 0.f, a1 = 0.f;
  unsigned uk=0, ue=0, uv=0;
  if(s0 < s1){
    int sn = ssrc[s0];
    if(act){
      uk = ((const unsigned*)(qkv + (size_t)sn*300 + 100))[lane];
      ue = ((const unsigned*)(ehc + (size_t)s0*100))[lane];
      uv = ((const unsigned*)(qkv + (size_t)sn*300 + 200))[lane];
    }
  }
  for(int j=s0; j<s1; j++){
    unsigned cuk=uk, cue=ue, cuv=uv;
    int nj = j+1;
    if(nj < s1){
      int sn2 = ssrc[nj];
      if(act){
        uk = ((const unsigned*)(qkv + (size_t)sn2*300 + 100))[lane];
        ue = ((const unsigned*)(ehc + (size_t)nj*100))[lane];
        uv = ((const unsigned*)(qkv + (size_t)sn2*300 + 200))[lane];
      }
    }
    float p = 0.f, e0=0.f, e1=0.f;
    if(act){
      e0=u2f_lo(cue); e1=u2f_hi(cue);
      p = q0*(u2f_lo(cuk)+e0) + q1*(u2f_hi(cuk)+e1);
    }
    for(int off=32; off; off>>=1) p += __shfl_xor(p, off);
    float alpha = p * 0.1f;
    float mn = fmaxf(m, alpha);
    float sc = __expf(m - mn);
    float wv = __expf(alpha - mn);
    d = d*sc + wv;
    if(act){
      a0 = a0*sc + wv*(u2f_lo(cuv)+e0);
      a1 = a1*sc + wv*(u2f_hi(cuv)+e1);
    }
    m = mn;
  }
  if(act){
    float inv = 1.f/(d + 1e-16f);
    unsigned us = ((const unsigned*)(hout + (size_t)node*ldh + colofs))[lane];
    float h0 = fmaxf(u2f_lo(us) + a0*inv, 0.f);
    float h1 = fmaxf(u2f_hi(us) + a1*inv, 0.f);
    bf16* op = hout + (size_t)node*ldh + colofs + lane*2;
    op[0] = f2b(h0); op[1] = f2b(h1);
  } else if(zpad && lane < 56){
    bf16* op = hout + (size_t)node*ldh + colofs + lane*2;
    op[0] = f2b(0.f); op[1] = f2b(0.f);
  }
}

// ------ linkpred final layer: out[e] = t3[e] @ w4 + b4 (K=50, N=2, fp32) ------
__global__ void k_lpout(const bf16* __restrict__ t3, const float* __restrict__ w4,
                        const float* __restrict__ b4, float* __restrict__ out,
                        int base, int n){
  int i = blockIdx.x*blockDim.x + threadIdx.x;
  if(i >= n*2) return;
  int g = i>>1, j = i&1;
  const bf16* tp = t3 + (size_t)g*50;
  float s = 0.f;
  for(int k=0;k<50;k++) s += b2f(tp[k])*w4[k*2+j];
  out[(size_t)(base+g)*2 + j] = s + b4[j];
}

extern "C" void kernel_launch(void* const* d_in, const int* in_sizes, int n_in,
                              void* d_out, int out_size, void* d_ws, size_t ws_size,
                              hipStream_t stream){
  const float* x       = (const float*)d_in[0];
  const float* msg     = (const float*)d_in[1];
  const float* time_w  = (const float*)d_in[2];
  const float* time_b  = (const float*)d_in[3];
  const float* c1_qw=(const float*)d_in[4];  const float* c1_qb=(const float*)d_in[5];
  const float* c1_kw=(const float*)d_in[6];  const float* c1_kb=(const float*)d_in[7];
  const float* c1_vw=(const float*)d_in[8];  const float* c1_vb=(const float*)d_in[9];
  const float* c1_ew=(const float*)d_in[10];
  const float* c1_sw=(const float*)d_in[11]; const float* c1_sb=(const float*)d_in[12];
  const float* c2_qw=(const float*)d_in[13]; const float* c2_qb=(const float*)d_in[14];
  const float* c2_kw=(const float*)d_in[15]; const float* c2_kb=(const float*)d_in[16];
  const float* c2_vw=(const float*)d_in[17]; const float* c2_vb=(const float*)d_in[18];
  const float* c2_ew=(const float*)d_in[19];
  const float* c2_sw=(const float*)d_in[20]; const float* c2_sb=(const float*)d_in[21];
  const float* lp_src_w=(const float*)d_in[22]; const float* lp_src_b=(const float*)d_in[23];
  const float* lp_dst_w=(const float*)d_in[24]; const float* lp_dst_b=(const float*)d_in[25];
  const float* lp1_w=(const float*)d_in[26]; const float* lp1_b=(const float*)d_in[27];
  const float* lp2_w=(const float*)d_in[28]; const float* lp2_b=(const float*)d_in[29];
  const float* lp3_w=(const float*)d_in[30]; const float* lp3_b=(const float*)d_in[31];
  const float* lp4_w=(const float*)d_in[32]; const float* lp4_b=(const float*)d_in[33];
  const int* last_update=(const int*)d_in[34];
  const int* tt =(const int*)d_in[35];
  const int* edge_index=(const int*)d_in[36];
  const int* src = edge_index;
  const int* dst = edge_index + EE;
  float* out = (float*)d_out;

  // ---- workspace (peak ~199.4 MB, < proved-safe 201.8 MB) ----
  char* ws = (char*)d_ws;
  bf16*  h1    = (bf16*) (ws + 0);             // N*800 = 80,000,000
  bf16*  relc  = (bf16*) (ws + 80000000);      // E*112 = 33,600,000 (CSR order)
  bf16*  ehc   = (bf16*) (ws + 113600000);     // E*100 = 30,000,000 (CSR order)
  bf16*  qkv   = (bf16*) (ws + 143600000);     // N*300 = 30,000,000
  bf16*  h2p   = (bf16*) (ws + 183600000);     // N*112 = 11,200,000
  bf16*  xb    = (bf16*) (ws + 183600000);     // overlay: dead before h2p written
  int*   rowptr= (int*)  (ws + 194800000);
  int*   elist = (int*)  (ws + 195000064);
  int*   ssrc  = (int*)  (ws + 195600064);
  int*   deg   = (int*)  (ws + 196200064);
  int*   cursor= (int*)  (ws + 196400064);
  bf16* c1all  = (bf16*)(ws + 196600064);  // 8 x [320][128] = 655,360
  bf16* c1eall = (bf16*)(ws + 197255424);  // 8 x [112][256] = 458,752
  bf16* c1swt  = (bf16*)(ws + 197714176);  // [800][128]     = 204,800
  bf16* c2all  = (bf16*)(ws + 197918976);  // [320][800]     = 512,000
  bf16* c2swt  = (bf16*)(ws + 198430976);  // [112][800]     = 179,200
  bf16* c2e    = (bf16*)(ws + 198610176);  // [112][256]     = 57,344
  bf16* lp1tF  = (bf16*)(ws + 198667520);  // [800][224]     = 358,400
  bf16* lp2t   = (bf16*)(ws + 199025920);  // [224][800]     = 358,400
  bf16* lp3t   = (bf16*)(ws + 199384320);  // [64][224]      = 28,672
  float* c1ball= (float*)(ws + 199412992); // [8][300]       = 9,600
  float* c2ball= (float*)(ws + 199422592); // [300]          = 1,200
  float* lp1c  = (float*)(ws + 199423808); // [800]          = 3,200
  bf16* zbuf   = (bf16*)(ws + 199427008);  // 64 B zeros -> ends 199,427,072
  // linkpred-phase overlays (conv buffers 0..173.6MB dead; h2p stays live):
  bf16* lt1 = (bf16*)(ws + 0);             // EH*800 = 120 MB
  bf16* lt2 = (bf16*)(ws + 120000000);     // EH*200 = 30 MB
  bf16* lt3 = (bf16*)(ws + 150000000);     // EH*50  = 7.5 MB

  // ---- weight conversion / folds ----
  k_wtc1<<<(8*320*128+255)/256,256,0,stream>>>(c1_qw,c1_kw,c1_vw,c1all);
  for(int h=0; h<8; h++)
    k_wte<<<(112*256+255)/256,256,0,stream>>>(c1_ew, 800, h*100, c1eall + (size_t)h*112*256);
  k_wte<<<(112*256+255)/256,256,0,stream>>>(c2_ew, 100, 0, c2e);
  k_wt2<<<(800*128+255)/256,256,0,stream>>>(c1_sw,100,800,0,800,c1swt,128,800);
  k_wt2<<<(100*800+255)/256,256,0,stream>>>(c2_qw,800,100,0,100,c2all,         800,100);
  k_wt2<<<(100*800+255)/256,256,0,stream>>>(c2_kw,800,100,0,100,c2all+100*800, 800,100);
  k_wt2<<<(100*800+255)/256,256,0,stream>>>(c2_vw,800,100,0,100,c2all+200*800, 800,100);
  k_wt2<<<(20*800+255)/256,256,0,stream>>>(c2_qw,800,100,0,0,   c2all+300*800, 800,20);
  k_wt2<<<(112*800+255)/256,256,0,stream>>>(c2_sw,800,100,0,100,c2swt,800,112);
  k_wt2<<<(224*800+255)/256,256,0,stream>>>(lp2_w,800,200,0,200,lp2t,800,224);
  k_wt2<<<(64*224+255)/256,256,0,stream>>>(lp3_w,200,50,0,50,lp3t,224,64);
  k_foldw<<<(800*224+255)/256,256,0,stream>>>(lp_src_w, lp_dst_w, lp1_w, lp1tF);
  k_foldb<<<(800+255)/256,256,0,stream>>>(lp_src_b, lp_dst_b, lp1_w, lp1_b, lp1c);
  k_bstack3<<<(8*300+255)/256,256,0,stream>>>(c1_qb,c1_kb,c1_vb,100,8,c1ball);
  k_bstack3<<<(300+255)/256,256,0,stream>>>(c2_qb,c2_kb,c2_vb,100,1,c2ball);
  k_zero<<<1,64,0,stream>>>((int*)zbuf, 16);
  k_cvtpad<<<(NN*112+255)/256,256,0,stream>>>(x, 100, xb, 112, NN*112);

  // ---- CSR build ----
  k_zero   <<<(NN+255)/256, 256, 0, stream>>>(deg, NN);
  k_zero   <<<(NN+255)/256, 256, 0, stream>>>(cursor, NN);
  k_hist   <<<(EE+255)/256, 256, 0, stream>>>(dst, deg);
  k_scan   <<<1, 1024, 0, stream>>>(deg, rowptr);
  k_scatter<<<(EE+255)/256, 256, 0, stream>>>(dst, src, rowptr, cursor, elist, ssrc);

  // ---- time encoding (CSR order; needs elist/ssrc) ----
  k_relenc<<<(EE*112+255)/256, 256, 0, stream>>>(elist, ssrc, tt, last_update,
                                                 time_w, time_b, relc);

  int gN = (NN + 127)/128;   // 391
  int gE = (EE + 127)/128;   // 1172
  int gL = (EH + 127)/128;   // 586
  int gA = (NN + 3)/4;

  // ---- conv1 skip: h1 = x@Sw_all + sb  (all 8 heads, N=800, 5 strips of 160) ----
  mm_tile<10><<<dim3(gN,5),256,0,stream>>>(xb,112,112,nullptr, 128,
      nullptr,0,0,nullptr, nullptr,0,0,
      c1swt,128, zbuf, c1_sb, h1,800, NN,800,0);

  // ---- conv1: per head = qkv GEMM (N=300) + reg-A edge GEMM + attention ----
  for(int h=0; h<8; h++){
    mm_tile<10><<<dim3(gN,2),256,0,stream>>>(xb,112,112,nullptr, 128,
        nullptr,0,0,nullptr, nullptr,0,0,
        c1all + (size_t)h*320*128, 128, zbuf, c1ball + h*300, qkv,300, NN,300,0);
    mm_edge<<<gE,256,0,stream>>>(relc, msg, elist,
        c1eall + (size_t)h*112*256, ehc,100, EE);
    k_attn<<<gA,256,0,stream>>>(rowptr, ssrc, qkv, ehc, h1, 800, h*100, 0);
  }

  // ---- conv2: qkv GEMM + edge GEMM + skip GEMM + attention ----
  mm_tile<10><<<dim3(gN,2),256,0,stream>>>(h1,800,800,nullptr, 800,
      nullptr,0,0,nullptr, nullptr,0,0,
      c2all,800, zbuf, c2ball, qkv,300, NN,300,0);
  mm_edge<<<gE,256,0,stream>>>(relc, msg, elist, c2e, ehc,100, EE);
  mm_tile<7><<<dim3(gN,1),256,0,stream>>>(h1,800,800,nullptr, 800,
      nullptr,0,0,nullptr, nullptr,0,0,
      c2swt,800, zbuf, c2_sb, h2p,112, NN,100,0);
  k_attn<<<gA,256,0,stream>>>(rowptr, ssrc, qkv, ehc, h2p, 112, 0, 1);

  // ---- link predictor (hh folded into t1): 2 edge-halves ----
  for(int half=0; half<2; half++){
    const int* esrc = src + half*EH;
    const int* edst = dst + half*EH;
    // t1 = tanh(h_src@U + h_dst@V + c): reg-gathered A, K=224, N=800 (5 strips)
    mm_gath<10><<<dim3(gL,5),256,0,stream>>>(h2p,112,112, esrc, edst,
        lp1tF, lp1c, lt1,800, EH,800,2);
    // t2 = tanh(t1@W2+b2): K=800, N=200 (2 strips of 112)
    mm_tile<7><<<dim3(gL,2),256,0,stream>>>(lt1,800,800,nullptr, 800,
        nullptr,0,0,nullptr, nullptr,0,0,
        lp2t,800, zbuf, lp2_b, lt2,200, EH,200,2);
    // t3 = tanh(t2@W3+b3): K=200(224), N=50
    mm_tile<4><<<dim3(gL,1),256,0,stream>>>(lt2,200,200,nullptr, 224,
        nullptr,0,0,nullptr, nullptr,0,0,
        lp3t,224, zbuf, lp3_b, lt3,50, EH,50,2);
    // out = t3@W4+b4
    k_lpout<<<(EH*2+255)/256,256,0,stream>>>(lt3, lp4_w, lp4_b, out, half*EH, EH);
  }

  (void)in_sizes; (void)n_in; (void)out_size; (void)ws_size;
}

// Round 13
// 1925.152 us; speedup vs baseline: 1.0379x; 1.0379x over previous
//
#include <hip/hip_runtime.h>
#include <hip/hip_bf16.h>
#include <math.h>

typedef __hip_bfloat16 bf16;
typedef short s16x8 __attribute__((ext_vector_type(8)));
typedef float f32x4 __attribute__((ext_vector_type(4)));

#define NN 50000
#define EE 150000
#define EH 75000   // linkpred edge-chunk (2 halves)

static __device__ __forceinline__ float b2f(bf16 x){ return __bfloat162float(x); }
static __device__ __forceinline__ bf16 f2b(float x){ return __float2bfloat16(x); }
static __device__ __forceinline__ short f2s(float x){
  union { bf16 b; short s; } u; u.b = f2b(x); return u.s;
}
static __device__ __forceinline__ float u2f_lo(unsigned u){ union{unsigned i;float f;}c; c.i=u<<16; return c.f; }
static __device__ __forceinline__ float u2f_hi(unsigned u){ union{unsigned i;float f;}c; c.i=u&0xffff0000u; return c.f; }

// fast tanh: 1 - 2/(e^{2|x|}+1), sign-restored. |err| ~1e-5 << bf16 quantum.
static __device__ __forceinline__ float fast_tanh(float x){
  float a = fabsf(x);
  float e = __expf(2.0f*a);
  float t = 1.0f - __fdividef(2.0f, e + 1.0f);
  return x < 0.f ? -t : t;
}

static __device__ __forceinline__ void gload_lds16(const void* g, void* l){
  __builtin_amdgcn_global_load_lds((const __attribute__((address_space(1))) void*)g,
                                   (__attribute__((address_space(3))) void*)l, 16, 0, 0);
}

template<int N> static __device__ __forceinline__ void wait_vmcnt(){
  if constexpr(N==0) asm volatile("s_waitcnt vmcnt(0)" ::: "memory");
  else if constexpr(N==1) asm volatile("s_waitcnt vmcnt(1)" ::: "memory");
  else if constexpr(N==2) asm volatile("s_waitcnt vmcnt(2)" ::: "memory");
  else if constexpr(N==3) asm volatile("s_waitcnt vmcnt(3)" ::: "memory");
  else if constexpr(N==4) asm volatile("s_waitcnt vmcnt(4)" ::: "memory");
  else if constexpr(N==5) asm volatile("s_waitcnt vmcnt(5)" ::: "memory");
  else asm volatile("s_waitcnt vmcnt(6)" ::: "memory");
}
static __device__ __forceinline__ void wait_lgkm0(){
  asm volatile("s_waitcnt lgkmcnt(0)" ::: "memory");
}
static __device__ __forceinline__ void memfence(){
  asm volatile("" ::: "memory");
}

// ---------------- utility ----------------
__global__ void k_zero(int* __restrict__ p, int n){
  int i = blockIdx.x*blockDim.x + threadIdx.x;
  if(i<n) p[i]=0;
}

// ---------------- CSR build ----------------
__global__ void k_hist(const int* __restrict__ dst, int* __restrict__ deg){
  int i = blockIdx.x*blockDim.x + threadIdx.x;
  if(i<EE) atomicAdd(&deg[dst[i]], 1);
}

__global__ void k_scan(const int* __restrict__ deg, int* __restrict__ rowptr){
  __shared__ int part[1024];
  int tid = threadIdx.x;
  const int n = NN;
  int chunk = (n + 1023)/1024;
  int start = tid*chunk;
  int end = start + chunk; if(end > n) end = n;
  int s = 0;
  for(int i=start;i<end;i++) s += deg[i];
  part[tid] = s; __syncthreads();
  for(int off=1; off<1024; off<<=1){
    int v = (tid>=off)? part[tid-off] : 0;
    __syncthreads();
    part[tid] += v;
    __syncthreads();
  }
  int run = (tid==0)? 0 : part[tid-1];
  for(int i=start;i<end;i++){ rowptr[i]=run; run += deg[i]; }
  if(tid==0) rowptr[n] = part[1023];
}

// also emits ssrc[j] = src[elist[j]] so attn streams src ids in CSR order
__global__ void k_scatter(const int* __restrict__ dst, const int* __restrict__ srcv,
                          const int* __restrict__ rowptr,
                          int* __restrict__ cursor, int* __restrict__ elist,
                          int* __restrict__ ssrc){
  int e = blockIdx.x*blockDim.x + threadIdx.x;
  if(e<EE){
    int d=dst[e]; int p=atomicAdd(&cursor[d],1);
    int pos = rowptr[d]+p;
    elist[pos]=e; ssrc[pos]=srcv[e];
  }
}

// ------- time encoding -> relc [E,112] in CSR ORDER (cols 100..111 zero) -------
__global__ void k_relenc(const int* __restrict__ elist, const int* __restrict__ ssrc,
                         const int* __restrict__ tt, const int* __restrict__ lu,
                         const float* __restrict__ tw, const float* __restrict__ tb,
                         bf16* __restrict__ rel){
  int i = blockIdx.x*blockDim.x + threadIdx.x;
  if(i >= EE*112) return;
  int j = i/112, c = i - j*112;
  float v = 0.f;
  if(c < 100){
    int e = elist[j];
    float rt  = (float)(lu[ssrc[j]] - tt[e]);
    float arg = __fadd_rn(__fmul_rn(rt, tw[c]), tb[c]);
    v = cosf(arg);
  }
  rel[i] = f2b(v);
}

// ------- fp32 [R][incols] -> bf16 [R][outcols] row-major, zero-padded ----
__global__ void k_cvtpad(const float* __restrict__ in, int incols,
                         bf16* __restrict__ outp, int outcols, int total){
  int i = blockIdx.x*blockDim.x + threadIdx.x;
  if(i >= total) return;
  int r = i/outcols, c = i - r*outcols;
  outp[i] = f2b(c < incols ? in[(size_t)r*incols + c] : 0.f);
}

// ------- generic weight transpose: WT[n][k] = W[k][colofs+n], bf16, zero-pad ----
__global__ void k_wt2(const float* __restrict__ W, int K, int N, int colofs, int ncols,
                      bf16* __restrict__ WT, int kpad, int nrows){
  int i = blockIdx.x*blockDim.x + threadIdx.x;
  if(i >= nrows*kpad) return;
  int n = i / kpad, k = i - n*kpad;
  float v = (n<ncols && k<K)? W[(size_t)k*N + colofs + n] : 0.f;
  WT[i] = f2b(v);
}

// ------- conv1 stacked qkv weights: 8 heads x [320 rows: q|k|v|pad][128] -----
__global__ void k_wtc1(const float* __restrict__ qw, const float* __restrict__ kw,
                       const float* __restrict__ vw, bf16* __restrict__ outp){
  int i = blockIdx.x*blockDim.x + threadIdx.x;
  if(i >= 8*320*128) return;
  int h = i/(320*128), r = (i/128)%320, k = i&127;
  float v = 0.f;
  if(r < 300 && k < 100){
    int s = r/100, n = r - s*100;
    const float* W = s==0? qw : s==1? kw : vw;
    v = W[(size_t)k*800 + h*100 + n];
  }
  outp[i] = f2b(v);
}

// ------- edge weights [112][256]: k<100 -> rel rows, 128..227 -> msg rows ---
// cols k in [100,128) and [228,256) are ZERO — mm_edge relies on this to
// neutralize clamped/garbage A lanes.
__global__ void k_wte(const float* __restrict__ ew, int N, int colofs,
                      bf16* __restrict__ outp){
  int i = blockIdx.x*blockDim.x + threadIdx.x;
  if(i >= 112*256) return;
  int r = i>>8, k = i&255;
  float v = 0.f;
  if(r < 100){
    if(k < 100) v = ew[(size_t)k*N + colofs + r];
    else if(k >= 128 && k < 228) v = ew[(size_t)(k-28)*N + colofs + r];
  }
  outp[i] = f2b(v);
}

// ------- stacked qkv bias: [H][3*W] ----------------
__global__ void k_bstack3(const float* __restrict__ b0, const float* __restrict__ b1,
                          const float* __restrict__ b2, int W, int H,
                          float* __restrict__ outp){
  int i = blockIdx.x*blockDim.x + threadIdx.x;
  if(i >= H*3*W) return;
  int h = i/(3*W), r = i - h*3*W, s = r/W, c = r - s*W;
  const float* b = s==0? b0 : s==1? b1 : b2;
  outp[i] = b[h*W + c];
}

// ------- linkpred fold: WT1f[n][k] bf16, [800][224] ------------------------------
__global__ void k_foldw(const float* __restrict__ sw, const float* __restrict__ dw,
                        const float* __restrict__ w1, bf16* __restrict__ o){
  int i = blockIdx.x*blockDim.x + threadIdx.x;
  if(i >= 800*224) return;
  int n = i/224, k = i - n*224;
  float s = 0.f;
  if(k < 100){
    for(int j=0;j<200;j++) s += sw[k*200+j]*w1[(size_t)j*800+n];
  } else if(k >= 112 && k < 212){
    int kk = k-112;
    for(int j=0;j<200;j++) s += dw[kk*200+j]*w1[(size_t)(200+j)*800+n];
  }
  o[i] = f2b(s);
}
__global__ void k_foldb(const float* __restrict__ sb, const float* __restrict__ db,
                        const float* __restrict__ w1, const float* __restrict__ b1,
                        float* __restrict__ o){
  int n = blockIdx.x*blockDim.x + threadIdx.x;
  if(n >= 800) return;
  float s = b1[n];
  for(int j=0;j<200;j++) s += sb[j]*w1[(size_t)j*800+n] + db[j]*w1[(size_t)(200+j)*800+n];
  o[n] = s;
}

// ---------------- counted-vmcnt ring-pipelined MFMA GEMM (BK=32, 3 bufs) --------
// (see R3 comments; one instantiation per kernel — R4 multi-inst segfaulted clang)
template<int NT>
static __device__ void mm_body(
    char* lds, int bx, int nstrip,
    const bf16* __restrict__ A1, int lda1, int kv1, const int* __restrict__ g1,
    int KS,
    const bf16* __restrict__ A2b, int lda2b, int kv2b, const int* __restrict__ g2,
    const float* __restrict__ A2f, int lda2f, int kv2f,
    const bf16* __restrict__ WT, int kpad,
    const bf16* __restrict__ zbuf,
    const float* __restrict__ bias,
    bf16* __restrict__ C, int ldc,
    int M, int nvalid, int act)
{
  constexpr int BN = NT*16;
  constexpr int BPASS = (BN*4 + 255)/256;
  constexpr int ABYTES = 8192;
  constexpr int BUFSZ = ABYTES + BPASS*4096;

  const int tid  = threadIdx.x;
  const int wave = tid>>6, lane = tid&63;
  const int quad = lane>>4, lo = lane&15;
  WT += (size_t)nstrip*BN*kpad;
  C  += (size_t)nstrip*BN;
  if(bias) bias += nstrip*BN;
  const int nval = nvalid - nstrip*BN;
  const int row0 = bx*128;

  float bvr[NT];
#pragma unroll
  for(int n=0;n<NT;n++){
    int col = n*16 + lo;
    bvr[n] = (bias && col < nval) ? bias[col] : 0.f;
  }
#pragma unroll
  for(int n=0;n<NT;n++) asm volatile("" :: "v"(bvr[n]));

  const char*  a1b[2];
  const char*  a2bp[2];
  const float* f2base[2];
  int acol0[2];
#pragma unroll
  for(int p=0;p<2;p++){
    int s = p*256 + tid;
    int row = s>>2, cp = s&3;
    int q = cp ^ ((row>>1)&3);
    int col0 = q*8;
    int rg = row0 + row; if(rg > M-1) rg = M-1;
    int r1 = g1 ? g1[rg] : rg;
    int r2 = g2 ? g2[rg] : rg;
    acol0[p] = col0;
    a1b[p]   = (const char*)A1 + ((size_t)r1*lda1 + col0)*2;
    a2bp[p]  = A2b ? (const char*)A2b + ((size_t)r2*lda2b)*2 : nullptr;
    f2base[p]= A2f ? (A2f + (size_t)r2*lda2f) : nullptr;
  }
  const char* bbase[BPASS];
#pragma unroll
  for(int p=0;p<BPASS;p++){
    int s = p*256 + tid;
    int rb = s>>2; if(rb > BN-1) rb = BN-1;
    int cp = s&3;
    int lq = cp ^ ((rb>>1)&3);
    bbase[p] = (const char*)WT + ((size_t)rb*kpad + lq*8)*2;
  }

  f32x4 acc[2][NT];
#pragma unroll
  for(int m=0;m<2;m++)
#pragma unroll
    for(int n=0;n<NT;n++) acc[m][n] = (f32x4){0.f,0.f,0.f,0.f};

  float4 pf0[2], pf1[2];

  auto stageA1 = [&](char* buf, int kb){
#pragma unroll
    for(int p=0;p<2;p++){
      int k = kb + acol0[p];
      const char* s;
      if(k < KS) s = (k < kv1) ? (a1b[p] + (size_t)kb*2) : (const char*)zbuf;
      else { int o = k - KS; s = (o < kv2b) ? (a2bp[p] + (size_t)o*2) : (const char*)zbuf; }
      gload_lds16(s, buf + p*4096 + wave*1024);
    }
  };
  auto loadA2f = [&](int kb){
#pragma unroll
    for(int p=0;p<2;p++){
      int o = kb + acol0[p] - KS;
      const float* ap = f2base[p] + o;
      pf0[p] = (o   < kv2f) ? *(const float4*)ap     : (float4){0.f,0.f,0.f,0.f};
      pf1[p] = (o+4 < kv2f) ? *(const float4*)(ap+4) : (float4){0.f,0.f,0.f,0.f};
    }
  };
  auto writeA2 = [&](char* buf){
#pragma unroll
    for(int p=0;p<2;p++){
      s16x8 v;
      v[0]=f2s(pf0[p].x); v[1]=f2s(pf0[p].y); v[2]=f2s(pf0[p].z); v[3]=f2s(pf0[p].w);
      v[4]=f2s(pf1[p].x); v[5]=f2s(pf1[p].y); v[6]=f2s(pf1[p].z); v[7]=f2s(pf1[p].w);
      *(s16x8*)(buf + p*4096 + (size_t)tid*16) = v;
    }
  };
  auto stageB = [&](char* buf, int kb){
#pragma unroll
    for(int p=0;p<BPASS;p++)
      gload_lds16(bbase[p] + (size_t)kb*2, buf + ABYTES + p*4096 + wave*1024);
  };
  auto compute = [&](const char* buf){
    s16x8 af[2];
#pragma unroll
    for(int m=0;m<2;m++){
      int rl = wave*32 + m*16 + lo;
      int cp = quad ^ ((rl>>1)&3);
      af[m] = *(const s16x8*)(buf + rl*64 + cp*16);
    }
#pragma unroll
    for(int n=0;n<NT;n++){
      int rb = n*16 + lo;
      int cp = quad ^ ((rb>>1)&3);
      s16x8 bfr = *(const s16x8*)(buf + ABYTES + rb*64 + cp*16);
      acc[0][n] = __builtin_amdgcn_mfma_f32_16x16x32_bf16(af[0], bfr, acc[0][n], 0,0,0);
      acc[1][n] = __builtin_amdgcn_mfma_f32_16x16x32_bf16(af[1], bfr, acc[1][n], 0,0,0);
    }
  };

  const int T = kpad >> 5;
  stageA1(lds, 0); stageB(lds, 0);
  if(T > 1){ stageA1(lds + BUFSZ, 32); stageB(lds + BUFSZ, 32); }

  for(int t=0; t<T; t++){
    bool nb  = (t+1 < T);
    bool nfp = nb && A2f && (((t+1)<<5) >= KS);
    if(!nb)      wait_vmcnt<0>();
    else if(nfp) wait_vmcnt<BPASS>();
    else         wait_vmcnt<2+BPASS>();
    wait_lgkm0();
    __builtin_amdgcn_s_barrier();
    memfence();
    int tp = t+2;
    bool sp  = (tp < T);
    bool spf = sp && A2f && ((tp<<5) >= KS);
    char* nb3 = lds + (tp%3)*BUFSZ;
    if(sp){
      int kb2 = tp<<5;
      if(spf) loadA2f(kb2);
      else    stageA1(nb3, kb2);
      stageB(nb3, kb2);
    }
    compute(lds + (t%3)*BUFSZ);
    if(spf) writeA2(nb3);
  }

  const int r0 = (lane&1)<<1;
#pragma unroll
  for(int n=0;n<NT;n++){
    int col  = n*16 + lo;
    int pcol = col & ~1;
    bool cok = (pcol < nval);
    float bv = bvr[n];
#pragma unroll
    for(int m=0;m<2;m++){
      float v[4];
#pragma unroll
      for(int r=0;r<4;r++){
        float t = acc[m][n][r] + bv;
        if(act==1) t = fmaxf(t, 0.f);
        else if(act==2) t = fast_tanh(t);
        v[r] = t;
      }
      unsigned mylo = (unsigned)(unsigned short)f2s(v[r0])
                    | ((unsigned)(unsigned short)f2s(v[r0+1])<<16);
      unsigned snd  = (unsigned)(unsigned short)f2s(v[r0^2])
                    | ((unsigned)(unsigned short)f2s(v[(r0^2)+1])<<16);
      unsigned got  = (unsigned)__shfl_xor((int)snd, 1);
      unsigned w0, w1;
      if(lane&1){ w0 = (got & 0xffffu) | (mylo<<16); w1 = (got>>16) | (mylo & 0xffff0000u); }
      else      { w0 = (mylo & 0xffffu) | (got<<16); w1 = (mylo>>16) | (got & 0xffff0000u); }
      if(cok){
        int prow = row0 + wave*32 + m*16 + quad*4 + r0;
        if(prow   < M) *(unsigned*)(C + (size_t)prow*ldc + pcol) = w0;
        if(prow+1 < M) *(unsigned*)(C + (size_t)(prow+1)*ldc + pcol) = w1;
      }
    }
  }
}

// standalone wrapper — one instantiation per NT
template<int NT>
__global__ __launch_bounds__(256) void mm_tile(
    const bf16* A1, int lda1, int kv1, const int* g1, int KS,
    const bf16* A2b, int lda2b, int kv2b, const int* g2,
    const float* A2f, int lda2f, int kv2f,
    const bf16* WT, int kpad, const bf16* zbuf, const float* bias,
    bf16* C, int ldc, int M, int nvalid, int act)
{
  constexpr int BUFSZ = 8192 + ((NT*16*4+255)/256)*4096;
  __shared__ __align__(16) char lds[3*BUFSZ];
  mm_body<NT>(lds, blockIdx.x, blockIdx.y, A1,lda1,kv1,g1, KS,
              A2b,lda2b,kv2b,g2, A2f,lda2f,kv2f, WT,kpad, zbuf, bias,
              C,ldc, M,nvalid,act);
}

// ---------- reg-gathered-A GEMM for t1 (K=224 fixed, dual src/dst gather) -------
// A fragments loaded per-lane to REGISTERS (1 KB/wave in flight per instr) — all
// 14 loads issued up-front, drained once by the first counted wait (in-order
// vmcnt retirement). B streams through a 3-buffer LDS ring with counted vmcnt.
// k<KS -> A[gs[row]][k], else A[gd[row]][k-KS]. LDS = 3*BPASS*4KB only.
// blockIdx.y = n-strip (max TLP; R11's strip-loop variant cut FETCH 95->25 MB
// but lost occupancy 20.6->8.8% and ran 1.6x slower — latency-bound regime).
template<int NT>
__global__ __launch_bounds__(256) void mm_gath(
    const bf16* __restrict__ A, int lda, int KS,
    const int* __restrict__ gs, const int* __restrict__ gd,
    const bf16* __restrict__ WT,
    const float* __restrict__ bias,
    bf16* __restrict__ C, int ldc,
    int M, int nvalid, int act)
{
  constexpr int T = 7;           // kpad = 224
  constexpr int KPAD = 224;
  constexpr int BN = NT*16;
  constexpr int BPASS = (BN*4 + 255)/256;
  constexpr int BUFSZ = BPASS*4096;
  __shared__ __align__(16) char lds[3*BUFSZ];

  const int tid  = threadIdx.x;
  const int wave = tid>>6, lane = tid&63;
  const int quad = lane>>4, lo = lane&15;
  const int nstrip = blockIdx.y;
  const bf16* WTs = WT + (size_t)nstrip*BN*KPAD;
  C += (size_t)nstrip*BN;
  const float* bp = bias ? bias + nstrip*BN : nullptr;
  const int nval = nvalid - nstrip*BN;
  const int row0 = blockIdx.x*128;

  float bvr[NT];
#pragma unroll
  for(int n=0;n<NT;n++){
    int col = n*16 + lo;
    bvr[n] = (bp && col < nval) ? bp[col] : 0.f;
  }

  const bf16* abase[2][2];
#pragma unroll
  for(int m=0;m<2;m++){
    int r = row0 + wave*32 + m*16 + lo; if(r > M-1) r = M-1;
    abase[m][0] = A + (size_t)gs[r]*lda;
    abase[m][1] = A + (size_t)gd[r]*lda;
  }

  s16x8 areg[T][2];
#pragma unroll
  for(int t=0;t<T;t++){
#pragma unroll
    for(int m=0;m<2;m++){
      int k = t*32 + quad*8;
      const bf16* p = (k < KS) ? (abase[m][0] + k) : (abase[m][1] + (k - KS));
      asm volatile("global_load_dwordx4 %0, %1, off"
                   : "=v"(areg[t][m]) : "v"(p));
    }
  }
  memfence();

  const char* bbase[BPASS];
#pragma unroll
  for(int p=0;p<BPASS;p++){
    int s = p*256 + tid;
    int rb = s>>2; if(rb > BN-1) rb = BN-1;
    int cp = s&3;
    int lq = cp ^ ((rb>>1)&3);
    bbase[p] = (const char*)WTs + ((size_t)rb*KPAD + lq*8)*2;
  }
  auto stageB = [&](char* buf, int kb){
#pragma unroll
    for(int p=0;p<BPASS;p++)
      gload_lds16(bbase[p] + (size_t)kb*2, buf + p*4096 + wave*1024);
  };

  f32x4 acc[2][NT];
#pragma unroll
  for(int m=0;m<2;m++)
#pragma unroll
    for(int n=0;n<NT;n++) acc[m][n] = (f32x4){0.f,0.f,0.f,0.f};

  stageB(lds, 0);
  stageB(lds + BUFSZ, 32);

#pragma unroll
  for(int t=0; t<T; t++){
    if(t < T-1) wait_vmcnt<BPASS>();
    else        wait_vmcnt<0>();
    wait_lgkm0();
    __builtin_amdgcn_s_barrier();
    memfence();
    if(t+2 < T) stageB(lds + ((t+2)%3)*BUFSZ, (t+2)*32);
    const char* buf = lds + (t%3)*BUFSZ;
#pragma unroll
    for(int n=0;n<NT;n++){
      int rb = n*16 + lo;
      int cp = quad ^ ((rb>>1)&3);
      s16x8 bfr = *(const s16x8*)(buf + rb*64 + cp*16);
      acc[0][n] = __builtin_amdgcn_mfma_f32_16x16x32_bf16(areg[t][0], bfr, acc[0][n], 0,0,0);
      acc[1][n] = __builtin_amdgcn_mfma_f32_16x16x32_bf16(areg[t][1], bfr, acc[1][n], 0,0,0);
    }
  }

  const int r0 = (lane&1)<<1;
#pragma unroll
  for(int n=0;n<NT;n++){
    int col  = n*16 + lo;
    int pcol = col & ~1;
    bool cok = (pcol < nval);
    float bv = bvr[n];
#pragma unroll
    for(int m=0;m<2;m++){
      float v[4];
#pragma unroll
      for(int r=0;r<4;r++){
        float t = acc[m][n][r] + bv;
        if(act==1) t = fmaxf(t, 0.f);
        else if(act==2) t = fast_tanh(t);
        v[r] = t;
      }
      unsigned mylo = (unsigned)(unsigned short)f2s(v[r0])
                    | ((unsigned)(unsigned short)f2s(v[r0+1])<<16);
      unsigned snd  = (unsigned)(unsigned short)f2s(v[r0^2])
                    | ((unsigned)(unsigned short)f2s(v[(r0^2)+1])<<16);
      unsigned got  = (unsigned)__shfl_xor((int)snd, 1);
      unsigned w0, w1;
      if(lane&1){ w0 = (got & 0xffffu) | (mylo<<16); w1 = (got>>16) | (mylo & 0xffff0000u); }
      else      { w0 = (mylo & 0xffffu) | (got<<16); w1 = (mylo>>16) | (got & 0xffff0000u); }
      if(cok){
        int prow = row0 + wave*32 + m*16 + quad*4 + r0;
        if(prow   < M) *(unsigned*)(C + (size_t)prow*ldc + pcol) = w0;
        if(prow+1 < M) *(unsigned*)(C + (size_t)(prow+1)*ldc + pcol) = w1;
      }
    }
  }
}

// ---------- edge GEMM: ehc[j] = [relc[j] | msg[elist[j]]] @ WT  (K=256 fixed) ----
// All A fragments in REGISTERS up-front (8 relc bf16 frags + 16 msg float4s per
// lane, ~24 KB/wave in flight, drained once — in-order vmcnt retirement).
// B via 3-buffer LDS ring, counted vmcnt. Garbage/clamped A lanes are
// neutralized by WT's zero cols [100,128) & [228,256) (k_wte layout).
__global__ __launch_bounds__(256) void mm_edge(
    const bf16* __restrict__ relc,     // [EE][112], CSR order
    const float* __restrict__ msg,     // [EE][100], natural edge order
    const int* __restrict__ elist,
    const bf16* __restrict__ WT,       // [112][256]
    bf16* __restrict__ C, int ldc,     // ehc [EE][100]
    int M)
{
  constexpr int NT = 7;
  constexpr int BN = 112;
  constexpr int BPASS = 2;             // ceil(BN*4/256)
  constexpr int KPAD = 256, T = 8;
  constexpr int BUFSZ = BPASS*4096;
  __shared__ __align__(16) char lds[3*BUFSZ];

  const int tid  = threadIdx.x;
  const int wave = tid>>6, lane = tid&63;
  const int quad = lane>>4, lo = lane&15;
  const int row0 = blockIdx.x*128;

  // A row bases
  const bf16*  arel[2];
  const float* amsg[2];
#pragma unroll
  for(int m=0;m<2;m++){
    int r = row0 + wave*32 + m*16 + lo; if(r > M-1) r = M-1;
    arel[m] = relc + (size_t)r*112;
    amsg[m] = msg + (size_t)elist[r]*100;
  }

  // relc fragments, tiles 0..3 (k<112 valid; clamp to 96 -> garbage x zero-B)
  s16x8 ar[4][2];
#pragma unroll
  for(int t=0;t<4;t++){
#pragma unroll
    for(int m=0;m<2;m++){
      int k = t*32 + quad*8;
      int kc = (k < 112) ? k : 96;
      ar[t][m] = *(const s16x8*)(arel[m] + kc);
    }
  }
  // msg fragments, tiles 4..7 (fp32, masked; invalid lanes hit zero-B cols)
  float4 mf0[4][2], mf1[4][2];
#pragma unroll
  for(int t=0;t<4;t++){
#pragma unroll
    for(int m=0;m<2;m++){
      int mk = t*32 + quad*8;
      mf0[t][m] = (mk   < 100) ? *(const float4*)(amsg[m] + mk)   : (float4){0.f,0.f,0.f,0.f};
      mf1[t][m] = (mk+4 < 100) ? *(const float4*)(amsg[m] + mk+4) : (float4){0.f,0.f,0.f,0.f};
    }
  }
  memfence();

  // B ring
  const char* bbase[BPASS];
#pragma unroll
  for(int p=0;p<BPASS;p++){
    int s = p*256 + tid;
    int rb = s>>2; if(rb > BN-1) rb = BN-1;
    int cp = s&3;
    int lq = cp ^ ((rb>>1)&3);
    bbase[p] = (const char*)WT + ((size_t)rb*KPAD + lq*8)*2;
  }
  auto stageB = [&](char* buf, int kb){
#pragma unroll
    for(int p=0;p<BPASS;p++)
      gload_lds16(bbase[p] + (size_t)kb*2, buf + p*4096 + wave*1024);
  };

  f32x4 acc[2][NT];
#pragma unroll
  for(int m=0;m<2;m++)
#pragma unroll
    for(int n=0;n<NT;n++) acc[m][n] = (f32x4){0.f,0.f,0.f,0.f};

  stageB(lds, 0);
  stageB(lds + BUFSZ, 32);

#pragma unroll
  for(int t=0; t<T; t++){
    if(t < T-1) wait_vmcnt<BPASS>();
    else        wait_vmcnt<0>();
    wait_lgkm0();
    __builtin_amdgcn_s_barrier();
    memfence();
    if(t+2 < T) stageB(lds + ((t+2)%3)*BUFSZ, (t+2)*32);
    const char* buf = lds + (t%3)*BUFSZ;
    s16x8 af[2];
    if(t < 4){
#pragma unroll
      for(int m=0;m<2;m++) af[m] = ar[t][m];
    } else {
#pragma unroll
      for(int m=0;m<2;m++){
        float4 f0 = mf0[t-4][m], f1 = mf1[t-4][m];
        s16x8 v;
        v[0]=f2s(f0.x); v[1]=f2s(f0.y); v[2]=f2s(f0.z); v[3]=f2s(f0.w);
        v[4]=f2s(f1.x); v[5]=f2s(f1.y); v[6]=f2s(f1.z); v[7]=f2s(f1.w);
        af[m] = v;
      }
    }
#pragma unroll
    for(int n=0;n<NT;n++){
      int rb = n*16 + lo;
      int cp = quad ^ ((rb>>1)&3);
      s16x8 bfr = *(const s16x8*)(buf + rb*64 + cp*16);
      acc[0][n] = __builtin_amdgcn_mfma_f32_16x16x32_bf16(af[0], bfr, acc[0][n], 0,0,0);
      acc[1][n] = __builtin_amdgcn_mfma_f32_16x16x32_bf16(af[1], bfr, acc[1][n], 0,0,0);
    }
  }

  // epilogue: no bias, no act, nval = 100
  const int r0 = (lane&1)<<1;
#pragma unroll
  for(int n=0;n<NT;n++){
    int col  = n*16 + lo;
    int pcol = col & ~1;
    bool cok = (pcol < 100);
#pragma unroll
    for(int m=0;m<2;m++){
      float v[4];
#pragma unroll
      for(int r=0;r<4;r++) v[r] = acc[m][n][r];
      unsigned mylo = (unsigned)(unsigned short)f2s(v[r0])
                    | ((unsigned)(unsigned short)f2s(v[r0+1])<<16);
      unsigned snd  = (unsigned)(unsigned short)f2s(v[r0^2])
                    | ((unsigned)(unsigned short)f2s(v[(r0^2)+1])<<16);
      unsigned got  = (unsigned)__shfl_xor((int)snd, 1);
      unsigned w0, w1;
      if(lane&1){ w0 = (got & 0xffffu) | (mylo<<16); w1 = (got>>16) | (mylo & 0xffff0000u); }
      else      { w0 = (mylo & 0xffffu) | (got<<16); w1 = (mylo>>16) | (got & 0xffff0000u); }
      if(cok){
        int prow = row0 + wave*32 + m*16 + quad*4 + r0;
        if(prow   < M) *(unsigned*)(C + (size_t)prow*ldc + pcol) = w0;
        if(prow+1 < M) *(unsigned*)(C + (size_t)(prow+1)*ldc + pcol) = w1;
      }
    }
  }
}

// ------ fused attention: one wave per node; online softmax; skip-add + relu ------
__global__ __launch_bounds__(256) void k_attn(
    const int* __restrict__ rowptr, const int* __restrict__ ssrc,
    const bf16* __restrict__ qkv, const bf16* __restrict__ ehc,
    bf16* __restrict__ hout, int ldh, int colofs, int zpad)
{
  int wave = threadIdx.x>>6, lane = threadIdx.x&63;
  int node = blockIdx.x*4 + wave;
  if(node >= NN) return;
  bool act = (lane < 50);
  float q0=0.f, q1=0.f;
  const unsigned* qrow = (const unsigned*)(qkv + (size_t)node*300);
  if(act){ unsigned u = qrow[lane]; q0=u2f_lo(u); q1=u2f_hi(u); }
  int s0 = rowptr[node], s1 = rowptr[node+1];
  float m = -3.4e38f, d = 0.f, a0 = 0.f, a1 = 0.f;
  for(int j=s0; j<s1; j++){
    int sn = ssrc[j];
    float p = 0.f, e0=0.f, e1=0.f;
    if(act){
      unsigned uk = ((const unsigned*)(qkv + (size_t)sn*300 + 100))[lane];
      unsigned ue = ((const unsigned*)(ehc + (size_t)j*100))[lane];
      e0=u2f_lo(ue); e1=u2f_hi(ue);
      p = q0*(u2f_lo(uk)+e0) + q1*(u2f_hi(uk)+e1);
    }
    for(int off=32; off; off>>=1) p += __shfl_xor(p, off);
    float alpha = p * 0.1f;
    float mn = fmaxf(m, alpha);
    float sc = __expf(m - mn);
    float wv = __expf(alpha - mn);
    d = d*sc + wv;
    if(act){
      unsigned uv = ((const unsigned*)(qkv + (size_t)sn*300 + 200))[lane];
      a0 = a0*sc + wv*(u2f_lo(uv)+e0);
      a1 = a1*sc + wv*(u2f_hi(uv)+e1);
    }
    m = mn;
  }
  if(act){
    float inv = 1.f/(d + 1e-16f);
    unsigned us = ((const unsigned*)(hout + (size_t)node*ldh + colofs))[lane];
    float h0 = fmaxf(u2f_lo(us) + a0*inv, 0.f);
    float h1 = fmaxf(u2f_hi(us) + a1*inv, 0.f);
    bf16* op = hout + (size_t)node*ldh + colofs + lane*2;
    op[0] = f2b(h0); op[1] = f2b(h1);
  } else if(zpad && lane < 56){
    bf16* op = hout + (size_t)node*ldh + colofs + lane*2;
    op[0] = f2b(0.f); op[1] = f2b(0.f);
  }
}

// ------ linkpred final layer: out[e] = t3[e] @ w4 + b4 (K=50, N=2, fp32) ------
__global__ void k_lpout(const bf16* __restrict__ t3, const float* __restrict__ w4,
                        const float* __restrict__ b4, float* __restrict__ out,
                        int base, int n){
  int i = blockIdx.x*blockDim.x + threadIdx.x;
  if(i >= n*2) return;
  int g = i>>1, j = i&1;
  const bf16* tp = t3 + (size_t)g*50;
  float s = 0.f;
  for(int k=0;k<50;k++) s += b2f(tp[k])*w4[k*2+j];
  out[(size_t)(base+g)*2 + j] = s + b4[j];
}

extern "C" void kernel_launch(void* const* d_in, const int* in_sizes, int n_in,
                              void* d_out, int out_size, void* d_ws, size_t ws_size,
                              hipStream_t stream){
  const float* x       = (const float*)d_in[0];
  const float* msg     = (const float*)d_in[1];
  const float* time_w  = (const float*)d_in[2];
  const float* time_b  = (const float*)d_in[3];
  const float* c1_qw=(const float*)d_in[4];  const float* c1_qb=(const float*)d_in[5];
  const float* c1_kw=(const float*)d_in[6];  const float* c1_kb=(const float*)d_in[7];
  const float* c1_vw=(const float*)d_in[8];  const float* c1_vb=(const float*)d_in[9];
  const float* c1_ew=(const float*)d_in[10];
  const float* c1_sw=(const float*)d_in[11]; const float* c1_sb=(const float*)d_in[12];
  const float* c2_qw=(const float*)d_in[13]; const float* c2_qb=(const float*)d_in[14];
  const float* c2_kw=(const float*)d_in[15]; const float* c2_kb=(const float*)d_in[16];
  const float* c2_vw=(const float*)d_in[17]; const float* c2_vb=(const float*)d_in[18];
  const float* c2_ew=(const float*)d_in[19];
  const float* c2_sw=(const float*)d_in[20]; const float* c2_sb=(const float*)d_in[21];
  const float* lp_src_w=(const float*)d_in[22]; const float* lp_src_b=(const float*)d_in[23];
  const float* lp_dst_w=(const float*)d_in[24]; const float* lp_dst_b=(const float*)d_in[25];
  const float* lp1_w=(const float*)d_in[26]; const float* lp1_b=(const float*)d_in[27];
  const float* lp2_w=(const float*)d_in[28]; const float* lp2_b=(const float*)d_in[29];
  const float* lp3_w=(const float*)d_in[30]; const float* lp3_b=(const float*)d_in[31];
  const float* lp4_w=(const float*)d_in[32]; const float* lp4_b=(const float*)d_in[33];
  const int* last_update=(const int*)d_in[34];
  const int* tt =(const int*)d_in[35];
  const int* edge_index=(const int*)d_in[36];
  const int* src = edge_index;
  const int* dst = edge_index + EE;
  float* out = (float*)d_out;

  // ---- workspace (peak ~199.4 MB, < proved-safe 201.8 MB) ----
  char* ws = (char*)d_ws;
  bf16*  h1    = (bf16*) (ws + 0);             // N*800 = 80,000,000
  bf16*  relc  = (bf16*) (ws + 80000000);      // E*112 = 33,600,000 (CSR order)
  bf16*  ehc   = (bf16*) (ws + 113600000);     // E*100 = 30,000,000 (CSR order)
  bf16*  qkv   = (bf16*) (ws + 143600000);     // N*300 = 30,000,000
  bf16*  h2p   = (bf16*) (ws + 183600000);     // N*112 = 11,200,000
  bf16*  xb    = (bf16*) (ws + 183600000);     // overlay: dead before h2p written
  int*   rowptr= (int*)  (ws + 194800000);
  int*   elist = (int*)  (ws + 195000064);
  int*   ssrc  = (int*)  (ws + 195600064);
  int*   deg   = (int*)  (ws + 196200064);
  int*   cursor= (int*)  (ws + 196400064);
  bf16* c1all  = (bf16*)(ws + 196600064);  // 8 x [320][128] = 655,360
  bf16* c1eall = (bf16*)(ws + 197255424);  // 8 x [112][256] = 458,752
  bf16* c1swt  = (bf16*)(ws + 197714176);  // [800][128]     = 204,800
  bf16* c2all  = (bf16*)(ws + 197918976);  // [320][800]     = 512,000
  bf16* c2swt  = (bf16*)(ws + 198430976);  // [112][800]     = 179,200
  bf16* c2e    = (bf16*)(ws + 198610176);  // [112][256]     = 57,344
  bf16* lp1tF  = (bf16*)(ws + 198667520);  // [800][224]     = 358,400
  bf16* lp2t   = (bf16*)(ws + 199025920);  // [224][800]     = 358,400
  bf16* lp3t   = (bf16*)(ws + 199384320);  // [64][224]      = 28,672
  float* c1ball= (float*)(ws + 199412992); // [8][300]       = 9,600
  float* c2ball= (float*)(ws + 199422592); // [300]          = 1,200
  float* lp1c  = (float*)(ws + 199423808); // [800]          = 3,200
  bf16* zbuf   = (bf16*)(ws + 199427008);  // 64 B zeros -> ends 199,427,072
  // linkpred-phase overlays (conv buffers 0..173.6MB dead; h2p stays live):
  bf16* lt1 = (bf16*)(ws + 0);             // EH*800 = 120 MB
  bf16* lt2 = (bf16*)(ws + 120000000);     // EH*200 = 30 MB
  bf16* lt3 = (bf16*)(ws + 150000000);     // EH*50  = 7.5 MB

  // ---- weight conversion / folds ----
  k_wtc1<<<(8*320*128+255)/256,256,0,stream>>>(c1_qw,c1_kw,c1_vw,c1all);
  for(int h=0; h<8; h++)
    k_wte<<<(112*256+255)/256,256,0,stream>>>(c1_ew, 800, h*100, c1eall + (size_t)h*112*256);
  k_wte<<<(112*256+255)/256,256,0,stream>>>(c2_ew, 100, 0, c2e);
  k_wt2<<<(800*128+255)/256,256,0,stream>>>(c1_sw,100,800,0,800,c1swt,128,800);
  k_wt2<<<(100*800+255)/256,256,0,stream>>>(c2_qw,800,100,0,100,c2all,         800,100);
  k_wt2<<<(100*800+255)/256,256,0,stream>>>(c2_kw,800,100,0,100,c2all+100*800, 800,100);
  k_wt2<<<(100*800+255)/256,256,0,stream>>>(c2_vw,800,100,0,100,c2all+200*800, 800,100);
  k_wt2<<<(20*800+255)/256,256,0,stream>>>(c2_qw,800,100,0,0,   c2all+300*800, 800,20);
  k_wt2<<<(112*800+255)/256,256,0,stream>>>(c2_sw,800,100,0,100,c2swt,800,112);
  k_wt2<<<(224*800+255)/256,256,0,stream>>>(lp2_w,800,200,0,200,lp2t,800,224);
  k_wt2<<<(64*224+255)/256,256,0,stream>>>(lp3_w,200,50,0,50,lp3t,224,64);
  k_foldw<<<(800*224+255)/256,256,0,stream>>>(lp_src_w, lp_dst_w, lp1_w, lp1tF);
  k_foldb<<<(800+255)/256,256,0,stream>>>(lp_src_b, lp_dst_b, lp1_w, lp1_b, lp1c);
  k_bstack3<<<(8*300+255)/256,256,0,stream>>>(c1_qb,c1_kb,c1_vb,100,8,c1ball);
  k_bstack3<<<(300+255)/256,256,0,stream>>>(c2_qb,c2_kb,c2_vb,100,1,c2ball);
  k_zero<<<1,64,0,stream>>>((int*)zbuf, 16);
  k_cvtpad<<<(NN*112+255)/256,256,0,stream>>>(x, 100, xb, 112, NN*112);

  // ---- CSR build ----
  k_zero   <<<(NN+255)/256, 256, 0, stream>>>(deg, NN);
  k_zero   <<<(NN+255)/256, 256, 0, stream>>>(cursor, NN);
  k_hist   <<<(EE+255)/256, 256, 0, stream>>>(dst, deg);
  k_scan   <<<1, 1024, 0, stream>>>(deg, rowptr);
  k_scatter<<<(EE+255)/256, 256, 0, stream>>>(dst, src, rowptr, cursor, elist, ssrc);

  // ---- time encoding (CSR order; needs elist/ssrc) ----
  k_relenc<<<(EE*112+255)/256, 256, 0, stream>>>(elist, ssrc, tt, last_update,
                                                 time_w, time_b, relc);

  int gN = (NN + 127)/128;   // 391
  int gE = (EE + 127)/128;   // 1172
  int gL = (EH + 127)/128;   // 586
  int gA = (NN + 3)/4;

  // ---- conv1 skip: h1 = x@Sw_all + sb  (all 8 heads, N=800, 5 strips of 160) ----
  mm_tile<10><<<dim3(gN,5),256,0,stream>>>(xb,112,112,nullptr, 128,
      nullptr,0,0,nullptr, nullptr,0,0,
      c1swt,128, zbuf, c1_sb, h1,800, NN,800,0);

  // ---- conv1: per head = qkv GEMM (N=300) + reg-A edge GEMM + attention ----
  for(int h=0; h<8; h++){
    mm_tile<10><<<dim3(gN,2),256,0,stream>>>(xb,112,112,nullptr, 128,
        nullptr,0,0,nullptr, nullptr,0,0,
        c1all + (size_t)h*320*128, 128, zbuf, c1ball + h*300, qkv,300, NN,300,0);
    mm_edge<<<gE,256,0,stream>>>(relc, msg, elist,
        c1eall + (size_t)h*112*256, ehc,100, EE);
    k_attn<<<gA,256,0,stream>>>(rowptr, ssrc, qkv, ehc, h1, 800, h*100, 0);
  }

  // ---- conv2: qkv GEMM + edge GEMM + skip GEMM + attention ----
  mm_tile<10><<<dim3(gN,2),256,0,stream>>>(h1,800,800,nullptr, 800,
      nullptr,0,0,nullptr, nullptr,0,0,
      c2all,800, zbuf, c2ball, qkv,300, NN,300,0);
  mm_edge<<<gE,256,0,stream>>>(relc, msg, elist, c2e, ehc,100, EE);
  mm_tile<7><<<dim3(gN,1),256,0,stream>>>(h1,800,800,nullptr, 800,
      nullptr,0,0,nullptr, nullptr,0,0,
      c2swt,800, zbuf, c2_sb, h2p,112, NN,100,0);
  k_attn<<<gA,256,0,stream>>>(rowptr, ssrc, qkv, ehc, h2p, 112, 0, 1);

  // ---- link predictor (hh folded into t1): 2 edge-halves ----
  for(int half=0; half<2; half++){
    const int* esrc = src + half*EH;
    const int* edst = dst + half*EH;
    // t1 = tanh(h_src@U + h_dst@V + c): reg-gathered A, K=224, N=800 (5 strips)
    mm_gath<10><<<dim3(gL,5),256,0,stream>>>(h2p,112,112, esrc, edst,
        lp1tF, lp1c, lt1,800, EH,800,2);
    // t2 = tanh(t1@W2+b2): K=800, N=200 (2 strips of 112)
    mm_tile<7><<<dim3(gL,2),256,0,stream>>>(lt1,800,800,nullptr, 800,
        nullptr,0,0,nullptr, nullptr,0,0,
        lp2t,800, zbuf, lp2_b, lt2,200, EH,200,2);
    // t3 = tanh(t2@W3+b3): K=200(224), N=50
    mm_tile<4><<<dim3(gL,1),256,0,stream>>>(lt2,200,200,nullptr, 224,
        nullptr,0,0,nullptr, nullptr,0,0,
        lp3t,224, zbuf, lp3_b, lt3,50, EH,50,2);
    // out = t3@W4+b4
    k_lpout<<<(EH*2+255)/256,256,0,stream>>>(lt3, lp4_w, lp4_b, out, half*EH, EH);
  }

  (void)in_sizes; (void)n_in; (void)out_size; (void)ws_size;
}